// Round 18
// baseline (658.659 us; speedup 1.0000x reference)
//
#include <hip/hip_runtime.h>
#include <stdint.h>

#define DEVI __device__ __forceinline__

typedef unsigned short u16;
typedef unsigned int u32;
typedef __attribute__((ext_vector_type(4))) unsigned short u16x4;
typedef __attribute__((ext_vector_type(8))) unsigned short u16x8;
typedef __attribute__((ext_vector_type(4))) float f32x4;
typedef __attribute__((ext_vector_type(4))) _Float16 f16x4;
typedef __attribute__((ext_vector_type(8))) _Float16 f16x8;

static constexpr int NT = 4096;   // tokens
static constexpr int D  = 512;    // channels per head
static constexpr int NH = 4;      // heads
static constexpr int KS = 4;      // split-K for PV

DEVI u16 f2h(float f) {
  _Float16 h = (_Float16)f;
  union { _Float16 h; u16 u; } v; v.h = h;
  return v.u;
}
DEVI float h2f(u16 u) {
  union { u16 u; _Float16 h; } v; v.u = u;
  return (float)v.h;
}

// order-preserving float<->uint for atomicMax on floats (finite values encode > 0)
DEVI u32 enc_ord(float f) {
  u32 u = __float_as_uint(f);
  return (u & 0x80000000u) ? ~u : (u | 0x80000000u);
}
DEVI float dec_ord(u32 k) {
  u32 u = (k & 0x80000000u) ? (k ^ 0x80000000u) : ~k;
  return __uint_as_float(u);
}

DEVI void gld_lds16(const u16* g, u16* l) {
  __builtin_amdgcn_global_load_lds((const __attribute__((address_space(1))) void*)g,
                                   (__attribute__((address_space(3))) void*)l, 16, 0, 0);
}

enum { OUT_F32 = 0, OUT_F16 = 2, OUT_RES = 3, OUT_SMAX = 4, OUT_F16T = 5 };

// C[M,N] = A[M,K] @ B[N,K]^T  (f16 in, f32 acc). 128x128 tile, BK=32, 4 waves.
// OUT_SMAX: f16 C (direct) + f16 C^T (via LDS) + row/col maxes.
// OUT_F16T: f16 C (direct) + f16 C^T (via LDS).
// OUT_RES : f32 C = res + A@B^T, res selected per blockIdx.z (res/res2).
template<int OUT>
__global__ __launch_bounds__(256)
void gemm_bt(const u16* __restrict__ A, int lda, size_t zsA,
             const u16* __restrict__ B, int ldb, size_t zsB,
             void* __restrict__ Cp, int ldc, size_t zsC,
             const float* __restrict__ res, const float* __restrict__ res2, int K,
             u32* __restrict__ rmg, u32* __restrict__ cmg,
             u16* __restrict__ STp, int ldct, size_t zsT)
{
  constexpr bool DOT = (OUT == OUT_SMAX || OUT == OUT_F16T);
  __shared__ u16 As[128 * 32];
  __shared__ u16 Bs[128 * 32];
  __shared__ u32 rmaxs[128], cmaxs[128];
  __shared__ u16 Tt[DOT ? 128 * 72 : 8];   // 144B row stride (16B-aligned)
  A += blockIdx.z * zsA;
  B += blockIdx.z * zsB;
  const float* resz = (OUT == OUT_RES && blockIdx.z) ? res2 : res;
  const int tid = threadIdx.x;
  const int lane = tid & 63, w = tid >> 6;
  const int wr = w >> 1, wc = w & 1;
  const int m0 = blockIdx.y * 128, n0 = blockIdx.x * 128;

  if (OUT == OUT_SMAX && tid < 128) { rmaxs[tid] = 0u; cmaxs[tid] = 0u; }

  f32x4 acc[4][4] = {};

  for (int k0 = 0; k0 < K; k0 += 32) {
    __syncthreads();
#pragma unroll
    for (int p = 0; p < 2; ++p) {
      int id = p * 256 + tid;
      int row = id >> 2, q = id & 3;
      gld_lds16(A + (size_t)(m0 + row) * lda + k0 + q * 8, As + id * 8);
      gld_lds16(B + (size_t)(n0 + row) * ldb + k0 + q * 8, Bs + id * 8);
    }
    __syncthreads();
    f16x8 af[4], bfv[4];
#pragma unroll
    for (int i = 0; i < 4; ++i)
      af[i] = *(const f16x8*)(As + (wr * 64 + i * 16 + (lane & 15)) * 32 + (lane >> 4) * 8);
#pragma unroll
    for (int i = 0; i < 4; ++i)
      bfv[i] = *(const f16x8*)(Bs + (wc * 64 + i * 16 + (lane & 15)) * 32 + (lane >> 4) * 8);
#pragma unroll
    for (int i = 0; i < 4; ++i)
#pragma unroll
      for (int j = 0; j < 4; ++j)
        acc[i][j] = __builtin_amdgcn_mfma_f32_16x16x32_f16(af[i], bfv[j], acc[i][j], 0, 0, 0);
  }

  // direct C store (all variants; DOT uses u16)
#pragma unroll
  for (int i = 0; i < 4; ++i) {
    int rl0 = wr * 64 + i * 16 + (lane >> 4) * 4;
#pragma unroll
    for (int j = 0; j < 4; ++j) {
      int c = n0 + wc * 64 + j * 16 + (lane & 15);
#pragma unroll
      for (int e = 0; e < 4; ++e) {
        size_t idx = blockIdx.z * zsC + (size_t)(m0 + rl0 + e) * ldc + c;
        float v = acc[i][j][e];
        if (OUT == OUT_F32) ((float*)Cp)[idx] = v;
        if (OUT == OUT_F16 || DOT) ((u16*)Cp)[idx] = f2h(v);
        if (OUT == OUT_RES) ((float*)Cp)[idx] = resz[(size_t)(m0 + rl0 + e) * ldc + c] + v;
      }
    }
  }

  if (OUT == OUT_SMAX) {
    // ---- row/col maxes ----
#pragma unroll
    for (int i = 0; i < 4; ++i) {
      int rl0 = wr * 64 + i * 16 + (lane >> 4) * 4;
#pragma unroll
      for (int e = 0; e < 4; ++e) {
        float m = fmaxf(fmaxf(acc[i][0][e], acc[i][1][e]), fmaxf(acc[i][2][e], acc[i][3][e]));
        atomicMax(&rmaxs[rl0 + e], enc_ord(m));
      }
    }
#pragma unroll
    for (int j = 0; j < 4; ++j) {
      float m = -3e38f;
#pragma unroll
      for (int i = 0; i < 4; ++i)
#pragma unroll
        for (int e = 0; e < 4; ++e) m = fmaxf(m, acc[i][j][e]);
      atomicMax(&cmaxs[wc * 64 + j * 16 + (lane & 15)], enc_ord(m));
    }
    __syncthreads();
    if (tid < 128) {
      atomicMax(rmg + m0 + tid, rmaxs[tid]);
      atomicMax(cmg + n0 + tid, cmaxs[tid]);
    }
  }

  if (DOT) {
    // ---- C^T write via LDS (col layout), 2 half-m passes ----
#pragma unroll
    for (int half = 0; half < 2; ++half) {
      __syncthreads();
      if (wr == half) {
#pragma unroll
        for (int i = 0; i < 4; ++i) {
          int rl = i * 16 + (lane >> 4) * 4;          // local m within half (0..63)
#pragma unroll
          for (int j = 0; j < 4; ++j) {
            int cl = wc * 64 + j * 16 + (lane & 15);
            u16x4 v;
            v[0] = f2h(acc[i][j][0]); v[1] = f2h(acc[i][j][1]);
            v[2] = f2h(acc[i][j][2]); v[3] = f2h(acc[i][j][3]);
            *(u16x4*)&Tt[cl * 72 + rl] = v;
          }
        }
      }
      __syncthreads();
#pragma unroll
      for (int q = 0; q < 4; ++q) {
        int id2 = q * 256 + tid;
        int c = id2 >> 3, mm = (id2 & 7) * 8;
        u16x8 v = *(const u16x8*)&Tt[c * 72 + mm];
        *(u16x8*)(STp + blockIdx.z * zsT + (size_t)(n0 + c) * ldct + m0 + half * 64 + mm) = v;
      }
    }
  }
}

// PV, split-K, 32x128 tile, XCD-swizzled (2048 blocks = 8/CU):
// part[z][M][D] = f16(exp(S-mx) @ B^T);  lpart[z][m] = partial row sums (bx==0).
__global__ __launch_bounds__(256)
void pv(const u16* __restrict__ Sarg, const u32* __restrict__ mx_u,
        const u16* __restrict__ B,   // [D][NT]
        u16* __restrict__ part, float* __restrict__ lpart, int Ksl)
{
  __shared__ u16 As[32 * 40];
  __shared__ u16 Bs[128 * 32];
  __shared__ float ps[8][32];
  const int tid = threadIdx.x;
  const int lane = tid & 63, w = tid >> 6;

  // XCD-bijective swizzle: grid (4,128,4) = 2048; XCD c gets a contiguous 2048-row
  // m-range within one z-slice -> S working set 4MB fits per-XCD L2.
  const int lid = blockIdx.x + 4 * (blockIdx.y + 128 * blockIdx.z);
  const int swz = (lid & 7) * 256 + (lid >> 3);
  const int bx = swz & 3, by = (swz >> 2) & 127, bz = swz >> 9;

  const int m0 = by * 32, n0 = bx * 128;
  const int kb = bz * Ksl;

  const int rA = tid >> 3, kc4 = (tid & 7) * 4;   // 32 rows x 8 chunks of 4
  const float mxA = dec_ord(mx_u[m0 + rA]);
  const u16* S0 = Sarg + (size_t)(m0 + rA) * NT + kb + kc4;

  f32x4 acc[2][2] = {};
  float sacc = 0.f;

  f16x4 sv0 = *(const f16x4*)S0;   // prologue

  for (int k0 = 0; k0 < Ksl; k0 += 32) {
    __syncthreads();
    // B staging: two async 16B direct-to-LDS per thread
#pragma unroll
    for (int p = 0; p < 2; ++p) {
      int id = p * 256 + tid;
      int row = id >> 2, q = id & 3;
      gld_lds16(B + (size_t)(n0 + row) * NT + kb + k0 + q * 8, Bs + id * 8);
    }
    // prefetch next S tile (hides under exp chain + MFMA)
    f16x4 nx0;
    if (k0 + 32 < Ksl) nx0 = *(const f16x4*)(S0 + k0 + 32);
    // exp current S -> As
    {
      u16x4 pk;
      float rs = 0.f;
#pragma unroll
      for (int j = 0; j < 4; ++j) {
        float e = __expf((float)sv0[j] - mxA);
        rs += e; pk[j] = f2h(e);
      }
      *(u16x4*)(As + rA * 40 + kc4) = pk;
      sacc += rs;
    }
    __syncthreads();
    f16x8 af[2], bfv[2];
#pragma unroll
    for (int i = 0; i < 2; ++i)
      af[i] = *(const f16x8*)(As + (i * 16 + (lane & 15)) * 40 + (lane >> 4) * 8);
#pragma unroll
    for (int j = 0; j < 2; ++j)
      bfv[j] = *(const f16x8*)(Bs + (w * 32 + j * 16 + (lane & 15)) * 32 + (lane >> 4) * 8);
#pragma unroll
    for (int i = 0; i < 2; ++i)
#pragma unroll
      for (int j = 0; j < 2; ++j)
        acc[i][j] = __builtin_amdgcn_mfma_f32_16x16x32_f16(af[i], bfv[j], acc[i][j], 0, 0, 0);
    sv0 = nx0;
  }

  u16* out = part + (size_t)bz * NT * D;
#pragma unroll
  for (int i = 0; i < 2; ++i) {
    int r0 = m0 + i * 16 + (lane >> 4) * 4;
#pragma unroll
    for (int j = 0; j < 2; ++j) {
      int c = n0 + w * 32 + j * 16 + (lane & 15);
#pragma unroll
      for (int e = 0; e < 4; ++e)
        out[(size_t)(r0 + e) * D + c] = f2h(acc[i][j][e]);
    }
  }

  __syncthreads();
  ps[tid & 7][tid >> 3] = sacc;
  __syncthreads();
  if (bx == 0 && tid < 32) {
    float s = 0.f;
#pragma unroll
    for (int g = 0; g < 8; ++g) s += ps[g][tid];
    lpart[(size_t)bz * NT + m0 + tid] = s;
  }
}

// a0h += f16((0.25/Lk[m]) * sum_z pk[z]);  a1h += likewise (all f16 RMW, deterministic)
__global__ __launch_bounds__(256)
void reduce2(const u16* __restrict__ pk, const float* __restrict__ lk,
             const u16* __restrict__ pq, const float* __restrict__ lq,
             u16* __restrict__ a0h, u16* __restrict__ a1h)
{
  const size_t i = ((size_t)blockIdx.x * 256 + threadIdx.x) * 4;
  const int m = (int)(i >> 9);   // i / D
  const size_t zs = (size_t)NT * D;
  float Lk = 0.f, Lq = 0.f;
#pragma unroll
  for (int z = 0; z < KS; ++z) { Lk += lk[(size_t)z * NT + m]; Lq += lq[(size_t)z * NT + m]; }
  float s0 = 0.f, s1 = 0.f, s2 = 0.f, s3 = 0.f;
#pragma unroll
  for (int z = 0; z < KS; ++z) {
    u16x4 v = *(const u16x4*)(pk + z * zs + i);
    s0 += h2f(v[0]); s1 += h2f(v[1]); s2 += h2f(v[2]); s3 += h2f(v[3]);
  }
  float ck = 0.25f / Lk;
  u16x4 a = *(const u16x4*)(a0h + i);
  u16x4 na;
  na[0] = f2h(h2f(a[0]) + s0 * ck); na[1] = f2h(h2f(a[1]) + s1 * ck);
  na[2] = f2h(h2f(a[2]) + s2 * ck); na[3] = f2h(h2f(a[3]) + s3 * ck);
  *(u16x4*)(a0h + i) = na;
  s0 = s1 = s2 = s3 = 0.f;
#pragma unroll
  for (int z = 0; z < KS; ++z) {
    u16x4 v = *(const u16x4*)(pq + z * zs + i);
    s0 += h2f(v[0]); s1 += h2f(v[1]); s2 += h2f(v[2]); s3 += h2f(v[3]);
  }
  float cq = 0.25f / Lq;
  u16x4 b = *(const u16x4*)(a1h + i);
  u16x4 nb;
  nb[0] = f2h(h2f(b[0]) + s0 * cq); nb[1] = f2h(h2f(b[1]) + s1 * cq);
  nb[2] = f2h(h2f(b[2]) + s2 * cq); nb[3] = f2h(h2f(b[3]) + s3 * cq);
  *(u16x4*)(a1h + i) = nb;
}

// multi-buffer cast: blockIdx.z selects (src, dst, count); counts guarded
__global__ __launch_bounds__(256)
void cast_multi(const float* p0, const float* p1, const float* p2,
                const float* p3, const float* p4, const float* p5,
                u16* o0, u16* o1, u16* o2, u16* o3, u16* o4, u16* o5,
                int n0, int n1, int n2, int n3, int n4, int n5)
{
  const float* in; u16* out; int n;
  switch (blockIdx.z) {
    case 0: in = p0; out = o0; n = n0; break;
    case 1: in = p1; out = o1; n = n1; break;
    case 2: in = p2; out = o2; n = n2; break;
    case 3: in = p3; out = o3; n = n3; break;
    case 4: in = p4; out = o4; n = n4; break;
    default: in = p5; out = o5; n = n5; break;
  }
  int i = (blockIdx.x * 256 + threadIdx.x) * 8;
  if (i >= n) return;
  f32x4 a = *(const f32x4*)(in + i), b = *(const f32x4*)(in + i + 4);
  u16x8 s;
  s[0] = f2h(a[0]); s[1] = f2h(a[1]); s[2] = f2h(a[2]); s[3] = f2h(a[3]);
  s[4] = f2h(b[0]); s[5] = f2h(b[1]); s[6] = f2h(b[2]); s[7] = f2h(b[3]);
  *(u16x8*)(out + i) = s;
}

// out[c][r] = f16(in[r][c]);  64x64 tiles
__global__ __launch_bounds__(256)
void transpose_cast_f32(const float* __restrict__ in, int ldi,
                        u16* __restrict__ out, int ldo)
{
  __shared__ u16 t[64][72];
  int r0 = blockIdx.x * 64, c0 = blockIdx.y * 64;
  int t8 = threadIdx.x & 7, rr = threadIdx.x >> 3;
#pragma unroll
  for (int p = 0; p < 2; ++p) {
    int r = rr + p * 32;
    const float* src = in + (size_t)(r0 + r) * ldi + c0 + t8 * 8;
    f32x4 a = *(const f32x4*)src, b = *(const f32x4*)(src + 4);
    u16x8 s;
    s[0] = f2h(a[0]); s[1] = f2h(a[1]); s[2] = f2h(a[2]); s[3] = f2h(a[3]);
    s[4] = f2h(b[0]); s[5] = f2h(b[1]); s[6] = f2h(b[2]); s[7] = f2h(b[3]);
    *(u16x8*)&t[r][t8 * 8] = s;
  }
  __syncthreads();
#pragma unroll
  for (int p = 0; p < 2; ++p) {
    int c = rr + p * 32;
    u16x8 s;
#pragma unroll
    for (int j = 0; j < 8; ++j) s[j] = t[t8 * 8 + j][c];
    *(u16x8*)(out + (size_t)(c0 + c) * ldo + r0 + t8 * 8) = s;
  }
}

extern "C" void kernel_launch(void* const* d_in, const int* in_sizes, int n_in,
                              void* d_out, int out_size, void* d_ws, size_t ws_size,
                              hipStream_t stream)
{
  const float* x_k    = (const float*)d_in[0];
  const float* x_q    = (const float*)d_in[1];
  const float* k_w    = (const float*)d_in[2];
  const float* q_w    = (const float*)d_in[3];
  const float* attn_w = (const float*)d_in[4];
  const float* proj_w = (const float*)d_in[5];
  float* out0 = (float*)d_out;
  float* out1 = out0 + (size_t)NT * D;

  char* wptr = (char*)d_ws;
  auto alloc = [&](size_t bytes) { char* p = wptr; wptr += (bytes + 255) & ~(size_t)255; return p; };
  u16*   pb     = (u16*)  alloc((size_t)D * D * 2);
  u16*   pbT    = (u16*)  alloc((size_t)D * D * 2);
  u16*   XKall  = (u16*)  alloc((size_t)NT * NH * D * 2);   // [4096][2048]
  u16*   XKTall = (u16*)  alloc((size_t)NT * NH * D * 2);   // [2048][4096]
  u16*   XQTall = (u16*)  alloc((size_t)NT * NH * D * 2);   // [2048][4096]
  u16*   Kpall  = (u16*)  alloc((size_t)NH * NT * D * 2);   // [4][4096][512]
  u16*   partK  = (u16*)  alloc((size_t)KS * NT * D * 2);   // 16 MB f16 partials
  u16*   partQ  = (u16*)  alloc((size_t)KS * NT * D * 2);   // 16 MB
  u16*   agg0h  = (u16*)  alloc((size_t)NT * D * 2);        // f16 head accumulators
  u16*   agg1h  = (u16*)  alloc((size_t)NT * D * 2);        // contiguous with agg0h
  float* lk     = (float*)alloc((size_t)KS * NT * 4);
  float* lq     = (float*)alloc((size_t)KS * NT * 4);
  u32*   rowm_u = (u32*)  alloc((size_t)NH * NT * 4);       // per-head
  u32*   colm_u = (u32*)  alloc((size_t)NH * NT * 4);       // contiguous with rowm_u
  u16*   ST     = (u16*)  alloc((size_t)NT * NT * 2);       // S transposed, f16
  char*  Sreg   = alloc((size_t)NT * NT * 2);               // S f16; scratch aliased below
  u16*   S      = (u16*)Sreg;
  // prep-only scratch aliased into the (not yet used) S region (30MB <= 32MB)
  char* sp = Sreg;
  auto salloc = [&](size_t bytes) { char* p = sp; sp += (bytes + 255) & ~(size_t)255; return p; };
  u16* xkb   = (u16*)salloc((size_t)NT * D * 2);
  u16* xqb   = (u16*)salloc((size_t)NT * D * 2);
  u16* kwb   = (u16*)salloc((size_t)NH * D * D * 2);
  u16* qwb   = (u16*)salloc((size_t)NH * D * D * 2);
  u16* Abf   = (u16*)salloc((size_t)NH * D * D * 2);
  u16* XQall = (u16*)salloc((size_t)NT * NH * D * 2);

  // ---- prep: all f32->f16 casts in one z=6 launch ----
  cast_multi<<<dim3(NT * D / 2048, 1, 6), 256, 0, stream>>>(
      x_k, x_q, k_w, q_w, attn_w, proj_w,
      xkb, xqb, kwb, qwb, Abf, pb,
      NT * D, NT * D, NH * D * D, NH * D * D, NH * D * D, D * D);
  transpose_cast_f32<<<dim3(D / 64, D / 64), 256, 0, stream>>>(proj_w, D, pbT, D);

  // batched (strides within d_ws allocation only): z=0 -> XK (+XKT), z=1 -> XQ (+XQT)
  gemm_bt<OUT_F16T><<<dim3(NH * D / 128, NT / 128, 2), 256, 0, stream>>>(
      xkb, D, (size_t)(xqb - xkb), kwb, D, (size_t)(qwb - kwb),
      XKall, NH * D, (size_t)(XQall - XKall), nullptr, nullptr, D,
      nullptr, nullptr, XKTall, NT, (size_t)(XQTall - XKTall));
  gemm_bt<OUT_F16><<<dim3(D / 128, NT / 128, NH), 256, 0, stream>>>(
      XQall, NH * D, (size_t)D, Abf, D, (size_t)D * D, Kpall, D, (size_t)NT * D,
      nullptr, nullptr, D, nullptr, nullptr, nullptr, 0, 0);

  hipMemsetAsync(agg0h, 0, (size_t)2 * NT * D * 2, stream);   // f16 accumulators
  hipMemsetAsync(rowm_u, 0, (size_t)2 * NH * NT * 4, stream); // all heads' maxes

  // ---- per-head ----
  for (int h = 0; h < NH; ++h) {
    const u16* XKh  = XKall + (size_t)h * D;          // lda 2048
    const u16* XKTh = XKTall + (size_t)h * D * NT;    // ldb 4096
    const u16* XQTh = XQTall + (size_t)h * D * NT;
    const u16* Kph  = Kpall + (size_t)h * NT * D;     // ldb 512
    u32* rmh = rowm_u + (size_t)h * NT;
    u32* cmh = colm_u + (size_t)h * NT;

    // S = XK_h @ Kp_h^T  (f16), S^T, + fused row/col maxes
    gemm_bt<OUT_SMAX><<<dim3(NT / 128, NT / 128), 256, 0, stream>>>(
        XKh, NH * D, 0, Kph, D, 0, S, NT, 0, nullptr, nullptr, D,
        rmh, cmh, ST, NT, 0);

    // dir1: partK[z] = exp(S-rowm) @ XQ_h;  dir2: partQ[z] = exp(ST-colm) @ XK_h
    pv<<<dim3(D / 128, NT / 32, KS), 256, 0, stream>>>(
        S, rmh, XQTh, partK, lk, NT / KS);
    pv<<<dim3(D / 128, NT / 32, KS), 256, 0, stream>>>(
        ST, cmh, XKTh, partQ, lq, NT / KS);

    // deterministic merge + softmax normalization + head-mean accumulate (f16)
    reduce2<<<NT * D / 1024, 256, 0, stream>>>(partK, lk, partQ, lq, agg0h, agg1h);
  }

  // ---- final projections + residual (batched z=2; res/res2 selected per z) ----
  gemm_bt<OUT_RES><<<dim3(D / 128, NT / 128, 2), 256, 0, stream>>>(
      agg0h, D, (size_t)(agg1h - agg0h), pb, D, (size_t)(pbT - pb),
      out0, D, (size_t)NT * D, x_k, x_q, D, nullptr, nullptr, nullptr, 0, 0);
}

// Round 19
// 553.398 us; speedup vs baseline: 1.1902x; 1.1902x over previous
//
#include <hip/hip_runtime.h>
#include <stdint.h>

#define DEVI __device__ __forceinline__

typedef unsigned short u16;
typedef unsigned int u32;
typedef __attribute__((ext_vector_type(4))) unsigned short u16x4;
typedef __attribute__((ext_vector_type(8))) unsigned short u16x8;
typedef __attribute__((ext_vector_type(4))) float f32x4;
typedef __attribute__((ext_vector_type(8))) _Float16 f16x8;

static constexpr int NT = 4096;   // tokens
static constexpr int D  = 512;    // channels per head
static constexpr int NH = 4;      // heads
static constexpr int KS = 4;      // split-K for PV

DEVI u16 f2h(float f) {
  _Float16 h = (_Float16)f;
  union { _Float16 h; u16 u; } v; v.h = h;
  return v.u;
}
DEVI float h2f(u16 u) {
  union { u16 u; _Float16 h; } v; v.u = u;
  return (float)v.h;
}

// order-preserving float<->uint for atomicMax on floats (finite values encode > 0)
DEVI u32 enc_ord(float f) {
  u32 u = __float_as_uint(f);
  return (u & 0x80000000u) ? ~u : (u | 0x80000000u);
}
DEVI float dec_ord(u32 k) {
  u32 u = (k & 0x80000000u) ? (k ^ 0x80000000u) : ~k;
  return __uint_as_float(u);
}

DEVI void gld_lds16(const u16* g, u16* l) {
  __builtin_amdgcn_global_load_lds((const __attribute__((address_space(1))) void*)g,
                                   (__attribute__((address_space(3))) void*)l, 16, 0, 0);
}

enum { OUT_F32 = 0, OUT_F16 = 2, OUT_RES = 3, OUT_SMAX = 4, OUT_F16T = 5 };

// C[M,N] = A[M,K] @ B[N,K]^T  (f16 in, f32 acc). 128x128 tile, BK=32, 4 waves.
// OUT_SMAX: f16 C (direct) + f16 C^T (via LDS) + row/col maxes.
// OUT_F16T: f16 C (direct) + f16 C^T (via LDS).
// OUT_RES : f32 C = res + A@B^T, res selected per blockIdx.z (res/res2).
template<int OUT>
__global__ __launch_bounds__(256)
void gemm_bt(const u16* __restrict__ A, int lda, size_t zsA,
             const u16* __restrict__ B, int ldb, size_t zsB,
             void* __restrict__ Cp, int ldc, size_t zsC,
             const float* __restrict__ res, const float* __restrict__ res2, int K,
             u32* __restrict__ rmg, u32* __restrict__ cmg,
             u16* __restrict__ STp, int ldct, size_t zsT)
{
  constexpr bool DOT = (OUT == OUT_SMAX || OUT == OUT_F16T);
  __shared__ u16 As[128 * 32];
  __shared__ u16 Bs[128 * 32];
  __shared__ u32 rmaxs[128], cmaxs[128];
  __shared__ u16 Tt[DOT ? 128 * 72 : 8];   // 144B row stride (16B-aligned)
  A += blockIdx.z * zsA;
  B += blockIdx.z * zsB;
  const float* resz = (OUT == OUT_RES && blockIdx.z) ? res2 : res;
  const int tid = threadIdx.x;
  const int lane = tid & 63, w = tid >> 6;
  const int wr = w >> 1, wc = w & 1;
  const int m0 = blockIdx.y * 128, n0 = blockIdx.x * 128;

  if (OUT == OUT_SMAX && tid < 128) { rmaxs[tid] = 0u; cmaxs[tid] = 0u; }

  f32x4 acc[4][4] = {};

  for (int k0 = 0; k0 < K; k0 += 32) {
    __syncthreads();
#pragma unroll
    for (int p = 0; p < 2; ++p) {
      int id = p * 256 + tid;
      int row = id >> 2, q = id & 3;
      gld_lds16(A + (size_t)(m0 + row) * lda + k0 + q * 8, As + id * 8);
      gld_lds16(B + (size_t)(n0 + row) * ldb + k0 + q * 8, Bs + id * 8);
    }
    __syncthreads();
    f16x8 af[4], bfv[4];
#pragma unroll
    for (int i = 0; i < 4; ++i)
      af[i] = *(const f16x8*)(As + (wr * 64 + i * 16 + (lane & 15)) * 32 + (lane >> 4) * 8);
#pragma unroll
    for (int i = 0; i < 4; ++i)
      bfv[i] = *(const f16x8*)(Bs + (wc * 64 + i * 16 + (lane & 15)) * 32 + (lane >> 4) * 8);
#pragma unroll
    for (int i = 0; i < 4; ++i)
#pragma unroll
      for (int j = 0; j < 4; ++j)
        acc[i][j] = __builtin_amdgcn_mfma_f32_16x16x32_f16(af[i], bfv[j], acc[i][j], 0, 0, 0);
  }

  // direct C store (all variants; DOT uses u16)
#pragma unroll
  for (int i = 0; i < 4; ++i) {
    int rl0 = wr * 64 + i * 16 + (lane >> 4) * 4;
#pragma unroll
    for (int j = 0; j < 4; ++j) {
      int c = n0 + wc * 64 + j * 16 + (lane & 15);
#pragma unroll
      for (int e = 0; e < 4; ++e) {
        size_t idx = blockIdx.z * zsC + (size_t)(m0 + rl0 + e) * ldc + c;
        float v = acc[i][j][e];
        if (OUT == OUT_F32) ((float*)Cp)[idx] = v;
        if (OUT == OUT_F16 || DOT) ((u16*)Cp)[idx] = f2h(v);
        if (OUT == OUT_RES) ((float*)Cp)[idx] = resz[(size_t)(m0 + rl0 + e) * ldc + c] + v;
      }
    }
  }

  if (OUT == OUT_SMAX) {
    // ---- row/col maxes ----
#pragma unroll
    for (int i = 0; i < 4; ++i) {
      int rl0 = wr * 64 + i * 16 + (lane >> 4) * 4;
#pragma unroll
      for (int e = 0; e < 4; ++e) {
        float m = fmaxf(fmaxf(acc[i][0][e], acc[i][1][e]), fmaxf(acc[i][2][e], acc[i][3][e]));
        atomicMax(&rmaxs[rl0 + e], enc_ord(m));
      }
    }
#pragma unroll
    for (int j = 0; j < 4; ++j) {
      float m = -3e38f;
#pragma unroll
      for (int i = 0; i < 4; ++i)
#pragma unroll
        for (int e = 0; e < 4; ++e) m = fmaxf(m, acc[i][j][e]);
      atomicMax(&cmaxs[wc * 64 + j * 16 + (lane & 15)], enc_ord(m));
    }
    __syncthreads();
    if (tid < 128) {
      atomicMax(rmg + m0 + tid, rmaxs[tid]);
      atomicMax(cmg + n0 + tid, cmaxs[tid]);
    }
  }

  if (DOT) {
    // ---- C^T write via LDS (col layout), 2 half-m passes ----
#pragma unroll
    for (int half = 0; half < 2; ++half) {
      __syncthreads();
      if (wr == half) {
#pragma unroll
        for (int i = 0; i < 4; ++i) {
          int rl = i * 16 + (lane >> 4) * 4;          // local m within half (0..63)
#pragma unroll
          for (int j = 0; j < 4; ++j) {
            int cl = wc * 64 + j * 16 + (lane & 15);
            u16x4 v;
            v[0] = f2h(acc[i][j][0]); v[1] = f2h(acc[i][j][1]);
            v[2] = f2h(acc[i][j][2]); v[3] = f2h(acc[i][j][3]);
            *(u16x4*)&Tt[cl * 72 + rl] = v;
          }
        }
      }
      __syncthreads();
#pragma unroll
      for (int q = 0; q < 4; ++q) {
        int id2 = q * 256 + tid;
        int c = id2 >> 3, mm = (id2 & 7) * 8;
        u16x8 v = *(const u16x8*)&Tt[c * 72 + mm];
        *(u16x8*)(STp + blockIdx.z * zsT + (size_t)(n0 + c) * ldct + m0 + half * 64 + mm) = v;
      }
    }
  }
}

// PV, split-K, 64x128 tile, XCD-swizzled (1024 blocks): part[z][M][D] = f16(exp(S-mx)@B^T)
// lpart[z][m] = partial row sums (written by bx==0). S regs software-pipelined.
__global__ __launch_bounds__(256)
void pv(const u16* __restrict__ Sarg, const u32* __restrict__ mx_u,
        const u16* __restrict__ B,   // [D][NT]
        u16* __restrict__ part, float* __restrict__ lpart, int Ksl)
{
  __shared__ u16 As[64 * 40];
  __shared__ u16 Bs[128 * 32];
  __shared__ float ps[4][64];
  const int tid = threadIdx.x;
  const int lane = tid & 63, w = tid >> 6;
  const int wr = w >> 1, wc = w & 1;

  // XCD-bijective swizzle: grid (4,64,4) = 1024; each XCD gets one half z-slice
  // (contiguous y-range, all x) -> S working set ~4MB fits per-XCD L2.
  const int lid = blockIdx.x + 4 * (blockIdx.y + 64 * blockIdx.z);
  const int swz = (lid & 7) * 128 + (lid >> 3);
  const int bx = swz & 3, by = (swz >> 2) & 63, bz = swz >> 8;

  const int m0 = by * 64, n0 = bx * 128;
  const int kb = bz * Ksl;

  const int rA = tid >> 2, kc = (tid & 3) * 8;
  const float mxA = dec_ord(mx_u[m0 + rA]);
  const u16* S0 = Sarg + (size_t)(m0 + rA) * NT + kb + kc;

  f32x4 acc[2][4] = {};
  float sacc = 0.f;

  f16x8 sv0 = *(const f16x8*)S0;   // prologue

  for (int k0 = 0; k0 < Ksl; k0 += 32) {
    __syncthreads();
#pragma unroll
    for (int p = 0; p < 2; ++p) {
      int id = p * 256 + tid;
      int row = id >> 2, q = id & 3;
      gld_lds16(B + (size_t)(n0 + row) * NT + kb + k0 + q * 8, Bs + id * 8);
    }
    f16x8 nx0;
    if (k0 + 32 < Ksl) nx0 = *(const f16x8*)(S0 + k0 + 32);
    {
      u16x8 pk;
      float rs = 0.f;
#pragma unroll
      for (int j = 0; j < 8; ++j) {
        float e = __expf((float)sv0[j] - mxA);
        rs += e; pk[j] = f2h(e);
      }
      *(u16x8*)(As + rA * 40 + kc) = pk;
      sacc += rs;
    }
    __syncthreads();
    f16x8 af[2], bfv[4];
#pragma unroll
    for (int i = 0; i < 2; ++i)
      af[i] = *(const f16x8*)(As + (wr * 32 + i * 16 + (lane & 15)) * 40 + (lane >> 4) * 8);
#pragma unroll
    for (int j = 0; j < 4; ++j)
      bfv[j] = *(const f16x8*)(Bs + (wc * 64 + j * 16 + (lane & 15)) * 32 + (lane >> 4) * 8);
#pragma unroll
    for (int i = 0; i < 2; ++i)
#pragma unroll
      for (int j = 0; j < 4; ++j)
        acc[i][j] = __builtin_amdgcn_mfma_f32_16x16x32_f16(af[i], bfv[j], acc[i][j], 0, 0, 0);
    sv0 = nx0;
  }

  u16* out = part + (size_t)bz * NT * D;
#pragma unroll
  for (int i = 0; i < 2; ++i) {
    int r0 = m0 + wr * 32 + i * 16 + (lane >> 4) * 4;
#pragma unroll
    for (int j = 0; j < 4; ++j) {
      int c = n0 + wc * 64 + j * 16 + (lane & 15);
#pragma unroll
      for (int e = 0; e < 4; ++e)
        out[(size_t)(r0 + e) * D + c] = f2h(acc[i][j][e]);
    }
  }

  __syncthreads();
  ps[tid & 3][tid >> 2] = sacc;
  __syncthreads();
  if (bx == 0 && tid < 64) {
    lpart[(size_t)bz * NT + m0 + tid] =
        ps[0][tid] + ps[1][tid] + ps[2][tid] + ps[3][tid];
  }
}

// a0h += f16((0.25/Lk[m]) * sum_z pk[z]);  a1h += likewise (all f16 RMW, deterministic)
__global__ __launch_bounds__(256)
void reduce2(const u16* __restrict__ pk, const float* __restrict__ lk,
             const u16* __restrict__ pq, const float* __restrict__ lq,
             u16* __restrict__ a0h, u16* __restrict__ a1h)
{
  const size_t i = ((size_t)blockIdx.x * 256 + threadIdx.x) * 4;
  const int m = (int)(i >> 9);   // i / D
  const size_t zs = (size_t)NT * D;
  float Lk = 0.f, Lq = 0.f;
#pragma unroll
  for (int z = 0; z < KS; ++z) { Lk += lk[(size_t)z * NT + m]; Lq += lq[(size_t)z * NT + m]; }
  float s0 = 0.f, s1 = 0.f, s2 = 0.f, s3 = 0.f;
#pragma unroll
  for (int z = 0; z < KS; ++z) {
    u16x4 v = *(const u16x4*)(pk + z * zs + i);
    s0 += h2f(v[0]); s1 += h2f(v[1]); s2 += h2f(v[2]); s3 += h2f(v[3]);
  }
  float ck = 0.25f / Lk;
  u16x4 a = *(const u16x4*)(a0h + i);
  u16x4 na;
  na[0] = f2h(h2f(a[0]) + s0 * ck); na[1] = f2h(h2f(a[1]) + s1 * ck);
  na[2] = f2h(h2f(a[2]) + s2 * ck); na[3] = f2h(h2f(a[3]) + s3 * ck);
  *(u16x4*)(a0h + i) = na;
  s0 = s1 = s2 = s3 = 0.f;
#pragma unroll
  for (int z = 0; z < KS; ++z) {
    u16x4 v = *(const u16x4*)(pq + z * zs + i);
    s0 += h2f(v[0]); s1 += h2f(v[1]); s2 += h2f(v[2]); s3 += h2f(v[3]);
  }
  float cq = 0.25f / Lq;
  u16x4 b = *(const u16x4*)(a1h + i);
  u16x4 nb;
  nb[0] = f2h(h2f(b[0]) + s0 * cq); nb[1] = f2h(h2f(b[1]) + s1 * cq);
  nb[2] = f2h(h2f(b[2]) + s2 * cq); nb[3] = f2h(h2f(b[3]) + s3 * cq);
  *(u16x4*)(a1h + i) = nb;
}

// multi-buffer cast: blockIdx.z selects (src, dst, count); counts guarded
__global__ __launch_bounds__(256)
void cast_multi(const float* p0, const float* p1, const float* p2,
                const float* p3, const float* p4, const float* p5,
                u16* o0, u16* o1, u16* o2, u16* o3, u16* o4, u16* o5,
                int n0, int n1, int n2, int n3, int n4, int n5)
{
  const float* in; u16* out; int n;
  switch (blockIdx.z) {
    case 0: in = p0; out = o0; n = n0; break;
    case 1: in = p1; out = o1; n = n1; break;
    case 2: in = p2; out = o2; n = n2; break;
    case 3: in = p3; out = o3; n = n3; break;
    case 4: in = p4; out = o4; n = n4; break;
    default: in = p5; out = o5; n = n5; break;
  }
  int i = (blockIdx.x * 256 + threadIdx.x) * 8;
  if (i >= n) return;
  f32x4 a = *(const f32x4*)(in + i), b = *(const f32x4*)(in + i + 4);
  u16x8 s;
  s[0] = f2h(a[0]); s[1] = f2h(a[1]); s[2] = f2h(a[2]); s[3] = f2h(a[3]);
  s[4] = f2h(b[0]); s[5] = f2h(b[1]); s[6] = f2h(b[2]); s[7] = f2h(b[3]);
  *(u16x8*)(out + i) = s;
}

// out[c][r] = f16(in[r][c]);  64x64 tiles
__global__ __launch_bounds__(256)
void transpose_cast_f32(const float* __restrict__ in, int ldi,
                        u16* __restrict__ out, int ldo)
{
  __shared__ u16 t[64][72];
  int r0 = blockIdx.x * 64, c0 = blockIdx.y * 64;
  int t8 = threadIdx.x & 7, rr = threadIdx.x >> 3;
#pragma unroll
  for (int p = 0; p < 2; ++p) {
    int r = rr + p * 32;
    const float* src = in + (size_t)(r0 + r) * ldi + c0 + t8 * 8;
    f32x4 a = *(const f32x4*)src, b = *(const f32x4*)(src + 4);
    u16x8 s;
    s[0] = f2h(a[0]); s[1] = f2h(a[1]); s[2] = f2h(a[2]); s[3] = f2h(a[3]);
    s[4] = f2h(b[0]); s[5] = f2h(b[1]); s[6] = f2h(b[2]); s[7] = f2h(b[3]);
    *(u16x8*)&t[r][t8 * 8] = s;
  }
  __syncthreads();
#pragma unroll
  for (int p = 0; p < 2; ++p) {
    int c = rr + p * 32;
    u16x8 s;
#pragma unroll
    for (int j = 0; j < 8; ++j) s[j] = t[t8 * 8 + j][c];
    *(u16x8*)(out + (size_t)(c0 + c) * ldo + r0 + t8 * 8) = s;
  }
}

extern "C" void kernel_launch(void* const* d_in, const int* in_sizes, int n_in,
                              void* d_out, int out_size, void* d_ws, size_t ws_size,
                              hipStream_t stream)
{
  const float* x_k    = (const float*)d_in[0];
  const float* x_q    = (const float*)d_in[1];
  const float* k_w    = (const float*)d_in[2];
  const float* q_w    = (const float*)d_in[3];
  const float* attn_w = (const float*)d_in[4];
  const float* proj_w = (const float*)d_in[5];
  float* out0 = (float*)d_out;
  float* out1 = out0 + (size_t)NT * D;

  char* wptr = (char*)d_ws;
  auto alloc = [&](size_t bytes) { char* p = wptr; wptr += (bytes + 255) & ~(size_t)255; return p; };
  u16*   pb     = (u16*)  alloc((size_t)D * D * 2);
  u16*   pbT    = (u16*)  alloc((size_t)D * D * 2);
  u16*   XKall  = (u16*)  alloc((size_t)NT * NH * D * 2);   // [4096][2048]
  u16*   XKTall = (u16*)  alloc((size_t)NT * NH * D * 2);   // [2048][4096]
  u16*   XQTall = (u16*)  alloc((size_t)NT * NH * D * 2);   // [2048][4096]
  u16*   Kpall  = (u16*)  alloc((size_t)NH * NT * D * 2);   // [4][4096][512]
  u16*   partK  = (u16*)  alloc((size_t)KS * NT * D * 2);   // 16 MB f16 partials
  u16*   partQ  = (u16*)  alloc((size_t)KS * NT * D * 2);   // 16 MB
  u16*   agg0h  = (u16*)  alloc((size_t)NT * D * 2);        // f16 head accumulators
  u16*   agg1h  = (u16*)  alloc((size_t)NT * D * 2);        // contiguous with agg0h
  float* lk     = (float*)alloc((size_t)KS * NT * 4);
  float* lq     = (float*)alloc((size_t)KS * NT * 4);
  u32*   rowm_u = (u32*)  alloc((size_t)NH * NT * 4);       // per-head
  u32*   colm_u = (u32*)  alloc((size_t)NH * NT * 4);       // contiguous with rowm_u
  u16*   ST     = (u16*)  alloc((size_t)NT * NT * 2);       // S transposed, f16
  char*  Sreg   = alloc((size_t)NT * NT * 2);               // S f16; scratch aliased below
  u16*   S      = (u16*)Sreg;
  // prep-only scratch aliased into the (not yet used) S region (30MB <= 32MB)
  char* sp = Sreg;
  auto salloc = [&](size_t bytes) { char* p = sp; sp += (bytes + 255) & ~(size_t)255; return p; };
  u16* xkb   = (u16*)salloc((size_t)NT * D * 2);
  u16* xqb   = (u16*)salloc((size_t)NT * D * 2);
  u16* kwb   = (u16*)salloc((size_t)NH * D * D * 2);
  u16* qwb   = (u16*)salloc((size_t)NH * D * D * 2);
  u16* Abf   = (u16*)salloc((size_t)NH * D * D * 2);
  u16* XQall = (u16*)salloc((size_t)NT * NH * D * 2);

  // ---- prep: all f32->f16 casts in one z=6 launch ----
  cast_multi<<<dim3(NT * D / 2048, 1, 6), 256, 0, stream>>>(
      x_k, x_q, k_w, q_w, attn_w, proj_w,
      xkb, xqb, kwb, qwb, Abf, pb,
      NT * D, NT * D, NH * D * D, NH * D * D, NH * D * D, D * D);
  transpose_cast_f32<<<dim3(D / 64, D / 64), 256, 0, stream>>>(proj_w, D, pbT, D);

  // batched (strides within d_ws allocation only): z=0 -> XK (+XKT), z=1 -> XQ (+XQT)
  gemm_bt<OUT_F16T><<<dim3(NH * D / 128, NT / 128, 2), 256, 0, stream>>>(
      xkb, D, (size_t)(xqb - xkb), kwb, D, (size_t)(qwb - kwb),
      XKall, NH * D, (size_t)(XQall - XKall), nullptr, nullptr, D,
      nullptr, nullptr, XKTall, NT, (size_t)(XQTall - XKTall));
  gemm_bt<OUT_F16><<<dim3(D / 128, NT / 128, NH), 256, 0, stream>>>(
      XQall, NH * D, (size_t)D, Abf, D, (size_t)D * D, Kpall, D, (size_t)NT * D,
      nullptr, nullptr, D, nullptr, nullptr, nullptr, 0, 0);

  hipMemsetAsync(agg0h, 0, (size_t)2 * NT * D * 2, stream);   // f16 accumulators
  hipMemsetAsync(rowm_u, 0, (size_t)2 * NH * NT * 4, stream); // all heads' maxes

  // ---- per-head ----
  for (int h = 0; h < NH; ++h) {
    const u16* XKh  = XKall + (size_t)h * D;          // lda 2048
    const u16* XKTh = XKTall + (size_t)h * D * NT;    // ldb 4096
    const u16* XQTh = XQTall + (size_t)h * D * NT;
    const u16* Kph  = Kpall + (size_t)h * NT * D;     // ldb 512
    u32* rmh = rowm_u + (size_t)h * NT;
    u32* cmh = colm_u + (size_t)h * NT;

    // S = XK_h @ Kp_h^T  (f16), S^T, + fused row/col maxes
    gemm_bt<OUT_SMAX><<<dim3(NT / 128, NT / 128), 256, 0, stream>>>(
        XKh, NH * D, 0, Kph, D, 0, S, NT, 0, nullptr, nullptr, D,
        rmh, cmh, ST, NT, 0);

    // dir1: partK[z] = exp(S-rowm) @ XQ_h;  dir2: partQ[z] = exp(ST-colm) @ XK_h
    pv<<<dim3(D / 128, NT / 64, KS), 256, 0, stream>>>(
        S, rmh, XQTh, partK, lk, NT / KS);
    pv<<<dim3(D / 128, NT / 64, KS), 256, 0, stream>>>(
        ST, cmh, XKTh, partQ, lq, NT / KS);

    // deterministic merge + softmax normalization + head-mean accumulate (f16)
    reduce2<<<NT * D / 1024, 256, 0, stream>>>(partK, lk, partQ, lq, agg0h, agg1h);
  }

  // ---- final projections + residual (batched z=2; res/res2 selected per z) ----
  gemm_bt<OUT_RES><<<dim3(D / 128, NT / 128, 2), 256, 0, stream>>>(
      agg0h, D, (size_t)(agg1h - agg0h), pb, D, (size_t)(pbT - pb),
      out0, D, (size_t)NT * D, x_k, x_q, D, nullptr, nullptr, nullptr, 0, 0);
}

// Round 20
// 540.798 us; speedup vs baseline: 1.2179x; 1.0233x over previous
//
#include <hip/hip_runtime.h>
#include <stdint.h>

#define DEVI __device__ __forceinline__

typedef unsigned short u16;
typedef unsigned int u32;
typedef __attribute__((ext_vector_type(4))) unsigned short u16x4;
typedef __attribute__((ext_vector_type(8))) unsigned short u16x8;
typedef __attribute__((ext_vector_type(4))) float f32x4;
typedef __attribute__((ext_vector_type(8))) _Float16 f16x8;

static constexpr int NT = 4096;   // tokens
static constexpr int D  = 512;    // channels per head
static constexpr int NH = 4;      // heads
static constexpr int KS = 4;      // split-K for PV

DEVI u16 f2h(float f) {
  _Float16 h = (_Float16)f;
  union { _Float16 h; u16 u; } v; v.h = h;
  return v.u;
}
DEVI float h2f(u16 u) {
  union { u16 u; _Float16 h; } v; v.u = u;
  return (float)v.h;
}

// order-preserving float<->uint for atomicMax on floats (finite values encode > 0)
DEVI u32 enc_ord(float f) {
  u32 u = __float_as_uint(f);
  return (u & 0x80000000u) ? ~u : (u | 0x80000000u);
}
DEVI float dec_ord(u32 k) {
  u32 u = (k & 0x80000000u) ? (k ^ 0x80000000u) : ~k;
  return __uint_as_float(u);
}

DEVI void gld_lds16(const u16* g, u16* l) {
  __builtin_amdgcn_global_load_lds((const __attribute__((address_space(1))) void*)g,
                                   (__attribute__((address_space(3))) void*)l, 16, 0, 0);
}

enum { OUT_F32 = 0, OUT_F16 = 2, OUT_RES = 3, OUT_SMAX = 4, OUT_F16T = 5 };

// C[M,N] = A[M,K] @ B[N,K]^T  (f16 in, f32 acc). 128x128 tile, BK=32, 4 waves.
// OUT_SMAX: f16 C (direct) + f16 C^T (via LDS) + row/col maxes.
// OUT_F16T: f16 C (direct) + f16 C^T (via LDS).
// OUT_RES : f32 C = res + A@B^T, res selected per blockIdx.z (res/res2).
template<int OUT>
__global__ __launch_bounds__(256)
void gemm_bt(const u16* __restrict__ A, int lda, size_t zsA,
             const u16* __restrict__ B, int ldb, size_t zsB,
             void* __restrict__ Cp, int ldc, size_t zsC,
             const float* __restrict__ res, const float* __restrict__ res2, int K,
             u32* __restrict__ rmg, u32* __restrict__ cmg,
             u16* __restrict__ STp, int ldct, size_t zsT)
{
  constexpr bool DOT = (OUT == OUT_SMAX || OUT == OUT_F16T);
  __shared__ u16 As[128 * 32];
  __shared__ u16 Bs[128 * 32];
  __shared__ u32 rmaxs[128], cmaxs[128];
  __shared__ u16 Tt[DOT ? 128 * 72 : 8];   // 144B row stride (16B-aligned)
  A += blockIdx.z * zsA;
  B += blockIdx.z * zsB;
  const float* resz = (OUT == OUT_RES && blockIdx.z) ? res2 : res;
  const int tid = threadIdx.x;
  const int lane = tid & 63, w = tid >> 6;
  const int wr = w >> 1, wc = w & 1;
  const int m0 = blockIdx.y * 128, n0 = blockIdx.x * 128;

  if (OUT == OUT_SMAX && tid < 128) { rmaxs[tid] = 0u; cmaxs[tid] = 0u; }

  f32x4 acc[4][4] = {};

  for (int k0 = 0; k0 < K; k0 += 32) {
    __syncthreads();
#pragma unroll
    for (int p = 0; p < 2; ++p) {
      int id = p * 256 + tid;
      int row = id >> 2, q = id & 3;
      gld_lds16(A + (size_t)(m0 + row) * lda + k0 + q * 8, As + id * 8);
      gld_lds16(B + (size_t)(n0 + row) * ldb + k0 + q * 8, Bs + id * 8);
    }
    __syncthreads();
    f16x8 af[4], bfv[4];
#pragma unroll
    for (int i = 0; i < 4; ++i)
      af[i] = *(const f16x8*)(As + (wr * 64 + i * 16 + (lane & 15)) * 32 + (lane >> 4) * 8);
#pragma unroll
    for (int i = 0; i < 4; ++i)
      bfv[i] = *(const f16x8*)(Bs + (wc * 64 + i * 16 + (lane & 15)) * 32 + (lane >> 4) * 8);
#pragma unroll
    for (int i = 0; i < 4; ++i)
#pragma unroll
      for (int j = 0; j < 4; ++j)
        acc[i][j] = __builtin_amdgcn_mfma_f32_16x16x32_f16(af[i], bfv[j], acc[i][j], 0, 0, 0);
  }

  // direct C store (all variants; DOT uses u16)
#pragma unroll
  for (int i = 0; i < 4; ++i) {
    int rl0 = wr * 64 + i * 16 + (lane >> 4) * 4;
#pragma unroll
    for (int j = 0; j < 4; ++j) {
      int c = n0 + wc * 64 + j * 16 + (lane & 15);
#pragma unroll
      for (int e = 0; e < 4; ++e) {
        size_t idx = blockIdx.z * zsC + (size_t)(m0 + rl0 + e) * ldc + c;
        float v = acc[i][j][e];
        if (OUT == OUT_F32) ((float*)Cp)[idx] = v;
        if (OUT == OUT_F16 || DOT) ((u16*)Cp)[idx] = f2h(v);
        if (OUT == OUT_RES) ((float*)Cp)[idx] = resz[(size_t)(m0 + rl0 + e) * ldc + c] + v;
      }
    }
  }

  if (OUT == OUT_SMAX) {
    // ---- row/col maxes ----
#pragma unroll
    for (int i = 0; i < 4; ++i) {
      int rl0 = wr * 64 + i * 16 + (lane >> 4) * 4;
#pragma unroll
      for (int e = 0; e < 4; ++e) {
        float m = fmaxf(fmaxf(acc[i][0][e], acc[i][1][e]), fmaxf(acc[i][2][e], acc[i][3][e]));
        atomicMax(&rmaxs[rl0 + e], enc_ord(m));
      }
    }
#pragma unroll
    for (int j = 0; j < 4; ++j) {
      float m = -3e38f;
#pragma unroll
      for (int i = 0; i < 4; ++i)
#pragma unroll
        for (int e = 0; e < 4; ++e) m = fmaxf(m, acc[i][j][e]);
      atomicMax(&cmaxs[wc * 64 + j * 16 + (lane & 15)], enc_ord(m));
    }
    __syncthreads();
    if (tid < 128) {
      atomicMax(rmg + m0 + tid, rmaxs[tid]);
      atomicMax(cmg + n0 + tid, cmaxs[tid]);
    }
  }

  if (DOT) {
    // ---- C^T write via LDS (col layout), 2 half-m passes ----
#pragma unroll
    for (int half = 0; half < 2; ++half) {
      __syncthreads();
      if (wr == half) {
#pragma unroll
        for (int i = 0; i < 4; ++i) {
          int rl = i * 16 + (lane >> 4) * 4;          // local m within half (0..63)
#pragma unroll
          for (int j = 0; j < 4; ++j) {
            int cl = wc * 64 + j * 16 + (lane & 15);
            u16x4 v;
            v[0] = f2h(acc[i][j][0]); v[1] = f2h(acc[i][j][1]);
            v[2] = f2h(acc[i][j][2]); v[3] = f2h(acc[i][j][3]);
            *(u16x4*)&Tt[cl * 72 + rl] = v;
          }
        }
      }
      __syncthreads();
#pragma unroll
      for (int q = 0; q < 4; ++q) {
        int id2 = q * 256 + tid;
        int c = id2 >> 3, mm = (id2 & 7) * 8;
        u16x8 v = *(const u16x8*)&Tt[c * 72 + mm];
        *(u16x8*)(STp + blockIdx.z * zsT + (size_t)(n0 + c) * ldct + m0 + half * 64 + mm) = v;
      }
    }
  }
}

// Dual-direction PV, split-K, 64x128 tile, direction-major XCD swizzle.
// Grid (4,64,8) = 2048 blocks: dir1 (z<4) dispatches fully before dir2.
// LDS padded to 34.8KB -> 4 blocks/CU cap so the two directions only mix at the seam
// (R12's regression was full co-residency of both directions thrashing L2).
__global__ __launch_bounds__(256)
void pv2(const u16* __restrict__ S, const u16* __restrict__ ST,
         const u32* __restrict__ rowm_u, const u32* __restrict__ colm_u,
         const u16* __restrict__ BQ, const u16* __restrict__ BK,   // [D][NT]
         u16* __restrict__ partK, u16* __restrict__ partQ,
         float* __restrict__ lk, float* __restrict__ lq, int Ksl)
{
  __shared__ u16 As[64 * 40];
  __shared__ u16 Bs[128 * 32];
  __shared__ float ps[4][64];
  __shared__ u16 lds_pad[10240];   // occupancy cap (guarded ref below keeps it allocated)
  const int tid = threadIdx.x;
  const int lane = tid & 63, w = tid >> 6;
  const int wr = w >> 1, wc = w & 1;
  if (Ksl == 0) lds_pad[tid] = 0;  // never true at runtime; unprovable at compile time

  // bijective swizzle: lid = a + 8m + 1024d  ->  swz = a*128 + m + d*1024
  // XCD a processes a contiguous 128-swz chunk per direction = 4MB S(T) slice in its L2.
  const int lid = blockIdx.x + 4 * (blockIdx.y + 64 * blockIdx.z);
  const int swz = (lid & 7) * 128 + ((lid >> 3) & 127) + (lid >> 10) * 1024;
  const int bx = swz & 3, by = (swz >> 2) & 63, bz = (swz >> 8) & 3;
  const int dir = swz >> 10;

  const u16* Sarg = dir ? ST : S;
  const u32* mx_u = dir ? colm_u : rowm_u;
  const u16* B    = dir ? BK : BQ;
  u16* part       = dir ? partQ : partK;
  float* lpart    = dir ? lq : lk;

  const int m0 = by * 64, n0 = bx * 128;
  const int kb = bz * Ksl;

  const int rA = tid >> 2, kc = (tid & 3) * 8;
  const float mxA = dec_ord(mx_u[m0 + rA]);
  const u16* S0 = Sarg + (size_t)(m0 + rA) * NT + kb + kc;

  f32x4 acc[2][4] = {};
  float sacc = 0.f;

  f16x8 sv0 = *(const f16x8*)S0;   // prologue

  for (int k0 = 0; k0 < Ksl; k0 += 32) {
    __syncthreads();
#pragma unroll
    for (int p = 0; p < 2; ++p) {
      int id = p * 256 + tid;
      int row = id >> 2, q = id & 3;
      gld_lds16(B + (size_t)(n0 + row) * NT + kb + k0 + q * 8, Bs + id * 8);
    }
    f16x8 nx0;
    if (k0 + 32 < Ksl) nx0 = *(const f16x8*)(S0 + k0 + 32);
    {
      u16x8 pk;
      float rs = 0.f;
#pragma unroll
      for (int j = 0; j < 8; ++j) {
        float e = __expf((float)sv0[j] - mxA);
        rs += e; pk[j] = f2h(e);
      }
      *(u16x8*)(As + rA * 40 + kc) = pk;
      sacc += rs;
    }
    __syncthreads();
    f16x8 af[2], bfv[4];
#pragma unroll
    for (int i = 0; i < 2; ++i)
      af[i] = *(const f16x8*)(As + (wr * 32 + i * 16 + (lane & 15)) * 40 + (lane >> 4) * 8);
#pragma unroll
    for (int j = 0; j < 4; ++j)
      bfv[j] = *(const f16x8*)(Bs + (wc * 64 + j * 16 + (lane & 15)) * 32 + (lane >> 4) * 8);
#pragma unroll
    for (int i = 0; i < 2; ++i)
#pragma unroll
      for (int j = 0; j < 4; ++j)
        acc[i][j] = __builtin_amdgcn_mfma_f32_16x16x32_f16(af[i], bfv[j], acc[i][j], 0, 0, 0);
    sv0 = nx0;
  }

  u16* out = part + (size_t)bz * NT * D;
#pragma unroll
  for (int i = 0; i < 2; ++i) {
    int r0 = m0 + wr * 32 + i * 16 + (lane >> 4) * 4;
#pragma unroll
    for (int j = 0; j < 4; ++j) {
      int c = n0 + wc * 64 + j * 16 + (lane & 15);
#pragma unroll
      for (int e = 0; e < 4; ++e)
        out[(size_t)(r0 + e) * D + c] = f2h(acc[i][j][e]);
    }
  }

  __syncthreads();
  ps[tid & 3][tid >> 2] = sacc;
  __syncthreads();
  if (bx == 0 && tid < 64) {
    lpart[(size_t)bz * NT + m0 + tid] =
        ps[0][tid] + ps[1][tid] + ps[2][tid] + ps[3][tid];
  }
}

// a0h += f16((0.25/Lk[m]) * sum_z pk[z]);  a1h += likewise (all f16 RMW, deterministic)
__global__ __launch_bounds__(256)
void reduce2(const u16* __restrict__ pk, const float* __restrict__ lk,
             const u16* __restrict__ pq, const float* __restrict__ lq,
             u16* __restrict__ a0h, u16* __restrict__ a1h)
{
  const size_t i = ((size_t)blockIdx.x * 256 + threadIdx.x) * 4;
  const int m = (int)(i >> 9);   // i / D
  const size_t zs = (size_t)NT * D;
  float Lk = 0.f, Lq = 0.f;
#pragma unroll
  for (int z = 0; z < KS; ++z) { Lk += lk[(size_t)z * NT + m]; Lq += lq[(size_t)z * NT + m]; }
  float s0 = 0.f, s1 = 0.f, s2 = 0.f, s3 = 0.f;
#pragma unroll
  for (int z = 0; z < KS; ++z) {
    u16x4 v = *(const u16x4*)(pk + z * zs + i);
    s0 += h2f(v[0]); s1 += h2f(v[1]); s2 += h2f(v[2]); s3 += h2f(v[3]);
  }
  float ck = 0.25f / Lk;
  u16x4 a = *(const u16x4*)(a0h + i);
  u16x4 na;
  na[0] = f2h(h2f(a[0]) + s0 * ck); na[1] = f2h(h2f(a[1]) + s1 * ck);
  na[2] = f2h(h2f(a[2]) + s2 * ck); na[3] = f2h(h2f(a[3]) + s3 * ck);
  *(u16x4*)(a0h + i) = na;
  s0 = s1 = s2 = s3 = 0.f;
#pragma unroll
  for (int z = 0; z < KS; ++z) {
    u16x4 v = *(const u16x4*)(pq + z * zs + i);
    s0 += h2f(v[0]); s1 += h2f(v[1]); s2 += h2f(v[2]); s3 += h2f(v[3]);
  }
  float cq = 0.25f / Lq;
  u16x4 b = *(const u16x4*)(a1h + i);
  u16x4 nb;
  nb[0] = f2h(h2f(b[0]) + s0 * cq); nb[1] = f2h(h2f(b[1]) + s1 * cq);
  nb[2] = f2h(h2f(b[2]) + s2 * cq); nb[3] = f2h(h2f(b[3]) + s3 * cq);
  *(u16x4*)(a1h + i) = nb;
}

// multi-buffer cast: blockIdx.z selects (src, dst, count); counts guarded
__global__ __launch_bounds__(256)
void cast_multi(const float* p0, const float* p1, const float* p2,
                const float* p3, const float* p4, const float* p5,
                u16* o0, u16* o1, u16* o2, u16* o3, u16* o4, u16* o5,
                int n0, int n1, int n2, int n3, int n4, int n5)
{
  const float* in; u16* out; int n;
  switch (blockIdx.z) {
    case 0: in = p0; out = o0; n = n0; break;
    case 1: in = p1; out = o1; n = n1; break;
    case 2: in = p2; out = o2; n = n2; break;
    case 3: in = p3; out = o3; n = n3; break;
    case 4: in = p4; out = o4; n = n4; break;
    default: in = p5; out = o5; n = n5; break;
  }
  int i = (blockIdx.x * 256 + threadIdx.x) * 8;
  if (i >= n) return;
  f32x4 a = *(const f32x4*)(in + i), b = *(const f32x4*)(in + i + 4);
  u16x8 s;
  s[0] = f2h(a[0]); s[1] = f2h(a[1]); s[2] = f2h(a[2]); s[3] = f2h(a[3]);
  s[4] = f2h(b[0]); s[5] = f2h(b[1]); s[6] = f2h(b[2]); s[7] = f2h(b[3]);
  *(u16x8*)(out + i) = s;
}

// out[c][r] = f16(in[r][c]);  64x64 tiles
__global__ __launch_bounds__(256)
void transpose_cast_f32(const float* __restrict__ in, int ldi,
                        u16* __restrict__ out, int ldo)
{
  __shared__ u16 t[64][72];
  int r0 = blockIdx.x * 64, c0 = blockIdx.y * 64;
  int t8 = threadIdx.x & 7, rr = threadIdx.x >> 3;
#pragma unroll
  for (int p = 0; p < 2; ++p) {
    int r = rr + p * 32;
    const float* src = in + (size_t)(r0 + r) * ldi + c0 + t8 * 8;
    f32x4 a = *(const f32x4*)src, b = *(const f32x4*)(src + 4);
    u16x8 s;
    s[0] = f2h(a[0]); s[1] = f2h(a[1]); s[2] = f2h(a[2]); s[3] = f2h(a[3]);
    s[4] = f2h(b[0]); s[5] = f2h(b[1]); s[6] = f2h(b[2]); s[7] = f2h(b[3]);
    *(u16x8*)&t[r][t8 * 8] = s;
  }
  __syncthreads();
#pragma unroll
  for (int p = 0; p < 2; ++p) {
    int c = rr + p * 32;
    u16x8 s;
#pragma unroll
    for (int j = 0; j < 8; ++j) s[j] = t[t8 * 8 + j][c];
    *(u16x8*)(out + (size_t)(c0 + c) * ldo + r0 + t8 * 8) = s;
  }
}

extern "C" void kernel_launch(void* const* d_in, const int* in_sizes, int n_in,
                              void* d_out, int out_size, void* d_ws, size_t ws_size,
                              hipStream_t stream)
{
  const float* x_k    = (const float*)d_in[0];
  const float* x_q    = (const float*)d_in[1];
  const float* k_w    = (const float*)d_in[2];
  const float* q_w    = (const float*)d_in[3];
  const float* attn_w = (const float*)d_in[4];
  const float* proj_w = (const float*)d_in[5];
  float* out0 = (float*)d_out;
  float* out1 = out0 + (size_t)NT * D;

  char* wptr = (char*)d_ws;
  auto alloc = [&](size_t bytes) { char* p = wptr; wptr += (bytes + 255) & ~(size_t)255; return p; };
  u16*   pb     = (u16*)  alloc((size_t)D * D * 2);
  u16*   pbT    = (u16*)  alloc((size_t)D * D * 2);
  u16*   XKall  = (u16*)  alloc((size_t)NT * NH * D * 2);   // [4096][2048]
  u16*   XKTall = (u16*)  alloc((size_t)NT * NH * D * 2);   // [2048][4096]
  u16*   XQTall = (u16*)  alloc((size_t)NT * NH * D * 2);   // [2048][4096]
  u16*   Kpall  = (u16*)  alloc((size_t)NH * NT * D * 2);   // [4][4096][512]
  u16*   partK  = (u16*)  alloc((size_t)KS * NT * D * 2);   // 16 MB f16 partials
  u16*   partQ  = (u16*)  alloc((size_t)KS * NT * D * 2);   // 16 MB
  u16*   agg0h  = (u16*)  alloc((size_t)NT * D * 2);        // f16 head accumulators
  u16*   agg1h  = (u16*)  alloc((size_t)NT * D * 2);        // contiguous with agg0h
  float* lk     = (float*)alloc((size_t)KS * NT * 4);
  float* lq     = (float*)alloc((size_t)KS * NT * 4);
  u32*   rowm_u = (u32*)  alloc((size_t)NH * NT * 4);       // per-head
  u32*   colm_u = (u32*)  alloc((size_t)NH * NT * 4);       // contiguous with rowm_u
  u16*   ST     = (u16*)  alloc((size_t)NT * NT * 2);       // S transposed, f16
  char*  Sreg   = alloc((size_t)NT * NT * 2);               // S f16; scratch aliased below
  u16*   S      = (u16*)Sreg;
  // prep-only scratch aliased into the (not yet used) S region (30MB <= 32MB)
  char* sp = Sreg;
  auto salloc = [&](size_t bytes) { char* p = sp; sp += (bytes + 255) & ~(size_t)255; return p; };
  u16* xkb   = (u16*)salloc((size_t)NT * D * 2);
  u16* xqb   = (u16*)salloc((size_t)NT * D * 2);
  u16* kwb   = (u16*)salloc((size_t)NH * D * D * 2);
  u16* qwb   = (u16*)salloc((size_t)NH * D * D * 2);
  u16* Abf   = (u16*)salloc((size_t)NH * D * D * 2);
  u16* XQall = (u16*)salloc((size_t)NT * NH * D * 2);

  // ---- prep: all f32->f16 casts in one z=6 launch ----
  cast_multi<<<dim3(NT * D / 2048, 1, 6), 256, 0, stream>>>(
      x_k, x_q, k_w, q_w, attn_w, proj_w,
      xkb, xqb, kwb, qwb, Abf, pb,
      NT * D, NT * D, NH * D * D, NH * D * D, NH * D * D, D * D);
  transpose_cast_f32<<<dim3(D / 64, D / 64), 256, 0, stream>>>(proj_w, D, pbT, D);

  // batched (strides within d_ws allocation only): z=0 -> XK (+XKT), z=1 -> XQ (+XQT)
  gemm_bt<OUT_F16T><<<dim3(NH * D / 128, NT / 128, 2), 256, 0, stream>>>(
      xkb, D, (size_t)(xqb - xkb), kwb, D, (size_t)(qwb - kwb),
      XKall, NH * D, (size_t)(XQall - XKall), nullptr, nullptr, D,
      nullptr, nullptr, XKTall, NT, (size_t)(XQTall - XKTall));
  gemm_bt<OUT_F16><<<dim3(D / 128, NT / 128, NH), 256, 0, stream>>>(
      XQall, NH * D, (size_t)D, Abf, D, (size_t)D * D, Kpall, D, (size_t)NT * D,
      nullptr, nullptr, D, nullptr, nullptr, nullptr, 0, 0);

  hipMemsetAsync(agg0h, 0, (size_t)2 * NT * D * 2, stream);   // f16 accumulators
  hipMemsetAsync(rowm_u, 0, (size_t)2 * NH * NT * 4, stream); // all heads' maxes

  // ---- per-head ----
  for (int h = 0; h < NH; ++h) {
    const u16* XKh  = XKall + (size_t)h * D;          // lda 2048
    const u16* XKTh = XKTall + (size_t)h * D * NT;    // ldb 4096
    const u16* XQTh = XQTall + (size_t)h * D * NT;
    const u16* Kph  = Kpall + (size_t)h * NT * D;     // ldb 512
    u32* rmh = rowm_u + (size_t)h * NT;
    u32* cmh = colm_u + (size_t)h * NT;

    // S = XK_h @ Kp_h^T  (f16), S^T, + fused row/col maxes
    gemm_bt<OUT_SMAX><<<dim3(NT / 128, NT / 128), 256, 0, stream>>>(
        XKh, NH * D, 0, Kph, D, 0, S, NT, 0, nullptr, nullptr, D,
        rmh, cmh, ST, NT, 0);

    // both directions, one launch (dir-major dispatch, occupancy-capped):
    // partK[z]=exp(S-rowm)@XQ_h, partQ[z]=exp(ST-colm)@XK_h
    pv2<<<dim3(D / 128, NT / 64, 2 * KS), 256, 0, stream>>>(
        S, ST, rmh, cmh, XQTh, XKTh, partK, partQ, lk, lq, NT / KS);

    // deterministic merge + softmax normalization + head-mean accumulate (f16)
    reduce2<<<NT * D / 1024, 256, 0, stream>>>(partK, lk, partQ, lq, agg0h, agg1h);
  }

  // ---- final projections + residual (batched z=2; res/res2 selected per z) ----
  gemm_bt<OUT_RES><<<dim3(D / 128, NT / 128, 2), 256, 0, stream>>>(
      agg0h, D, (size_t)(agg1h - agg0h), pb, D, (size_t)(pbT - pb),
      out0, D, (size_t)NT * D, x_k, x_q, D, nullptr, nullptr, nullptr, 0, 0);
}